// Round 3
// baseline (855.302 us; speedup 1.0000x reference)
//
#include <hip/hip_runtime.h>

typedef __attribute__((ext_vector_type(8))) short short8;
typedef __attribute__((ext_vector_type(4))) float f32x4;

#define BB 8
#define TT 1024
#define NN 64
#define HH 8
#define LL 2
#define KSS 3
#define DD1 64
#define EPSV 1e-6f

#define MFMA16(a, b, c) __builtin_amdgcn_mfma_f32_16x16x32_bf16(a, b, c, 0, 0, 0)

// ---- truncation-based hi/lo bf16 split (hi error lands exactly in lo) ----
__device__ __forceinline__ void split1(float x, ushort& hi, ushort& lo) {
  uint u = __float_as_uint(x);
  hi = (ushort)(u >> 16);
  float hf = __uint_as_float(u & 0xffff0000u);
  lo = (ushort)(__float_as_uint(x - hf) >> 16);
}
// pack two values -> (hi packed, lo packed)
__device__ __forceinline__ uint pack2(float a, float b, uint& lo) {
  uint ua = __float_as_uint(a), ub = __float_as_uint(b);
  float ra = __uint_as_float(ua & 0xffff0000u);
  float rb = __uint_as_float(ub & 0xffff0000u);
  lo = (__float_as_uint(a - ra) >> 16) | (__float_as_uint(b - rb) & 0xffff0000u);
  return (ua >> 16) | (ub & 0xffff0000u);
}

// ---- swizzled 64x64 bf16 LDS tiles (16B-chunk XOR swizzle) ----
__device__ __forceinline__ void stage_tile(ushort* __restrict__ s,
                                           const ushort* __restrict__ g,
                                           int row_stride, int tid) {
#pragma unroll
  for (int i = 0; i < 2; ++i) {
    int idx = tid + i * 256;
    int r = idx >> 3, c = idx & 7;
    uint4 v = *(const uint4*)(g + (size_t)r * row_stride + c * 8);
    *(uint4*)(s + r * 64 + ((c ^ (r & 7)) << 3)) = v;
  }
}
__device__ __forceinline__ void load2(uint4* r, const ushort* __restrict__ g,
                                      int row_stride, int tid) {
#pragma unroll
  for (int i = 0; i < 2; ++i) {
    int idx = tid + i * 256;
    int rr = idx >> 3, c = idx & 7;
    r[i] = *(const uint4*)(g + (size_t)rr * row_stride + c * 8);
  }
}
__device__ __forceinline__ void store2(ushort* __restrict__ s, const uint4* r, int tid) {
#pragma unroll
  for (int i = 0; i < 2; ++i) {
    int idx = tid + i * 256;
    int rr = idx >> 3, c = idx & 7;
    *(uint4*)(s + rr * 64 + ((c ^ (rr & 7)) << 3)) = r[i];
  }
}
__device__ __forceinline__ short8 frag(const ushort* __restrict__ s, int row, int ch) {
  return *(const short8*)(s + row * 64 + ((ch ^ (row & 7)) << 3));
}

// ---------- small kernels ----------

__global__ void k_addpos(const float* __restrict__ in, const float* __restrict__ pe,
                         float* __restrict__ x, int total) {
  int idx = blockIdx.x * 256 + threadIdx.x;
  if (idx < total) {
    int tn = idx & (TT * NN - 1);
    x[idx] = in[idx] + pe[tn];
  }
}

__global__ void k_k3s(const float* __restrict__ K3, const float* __restrict__ sclwl,
                      float* __restrict__ K3s) {
  int idx = blockIdx.x * 256 + threadIdx.x;
  int n = idx >> 6, m = idx & 63;
  K3s[idx] = K3[n * 192 + m] * sclwl[0] + K3[n * 192 + 64 + m] * sclwl[1] +
             K3[n * 192 + 128 + m] * sclwl[2];
}

// transpose+split: src [mat][1024][64] f32 -> dh/dl [mat][64][1024] bf16 hi/lo
__global__ __launch_bounds__(256) void k_tsplit(const float* __restrict__ src,
                                                ushort* __restrict__ dh,
                                                ushort* __restrict__ dl) {
  __shared__ float st[64][65];
  int blk = blockIdx.x;
  int mat = blk >> 4, rt = blk & 15;
  int tid = threadIdx.x;
  size_t sbase = ((size_t)mat * TT + rt * 64) * 64;
#pragma unroll
  for (int i = 0; i < 4; ++i) {
    int idx = tid + i * 256;
    int r = idx >> 4, c4 = idx & 15;
    float4 v = *(const float4*)(src + sbase + r * 64 + c4 * 4);
    st[r][c4 * 4 + 0] = v.x; st[r][c4 * 4 + 1] = v.y;
    st[r][c4 * 4 + 2] = v.z; st[r][c4 * 4 + 3] = v.w;
  }
  __syncthreads();
  size_t obase = (size_t)mat * (64 * (size_t)TT) + rt * 64;
#pragma unroll
  for (int i = 0; i < 2; ++i) {
    int idx = tid + i * 256;
    int n = idx >> 3, c = idx & 7;
    uint hw[4], lw[4];
#pragma unroll
    for (int j = 0; j < 4; ++j) hw[j] = pack2(st[c * 8 + 2 * j][n], st[c * 8 + 2 * j + 1][n], lw[j]);
    *(uint4*)(dh + obase + (size_t)n * TT + c * 8) = make_uint4(hw[0], hw[1], hw[2], hw[3]);
    *(uint4*)(dl + obase + (size_t)n * TT + c * 8) = make_uint4(lw[0], lw[1], lw[2], lw[3]);
  }
}

// transpose+split Wlt: [L][512][64] f32 -> [L][64][512] bf16 hi/lo
__global__ __launch_bounds__(256) void k_tsplitW(const float* __restrict__ Wlt,
                                                 ushort* __restrict__ dh,
                                                 ushort* __restrict__ dl) {
  __shared__ float st[64][65];
  int blk = blockIdx.x;  // l*8 + rt
  int l = blk >> 3, rt = blk & 7;
  int tid = threadIdx.x;
  size_t sbase = ((size_t)l * 512 + rt * 64) * 64;
#pragma unroll
  for (int i = 0; i < 4; ++i) {
    int idx = tid + i * 256;
    int r = idx >> 4, c4 = idx & 15;
    float4 v = *(const float4*)(Wlt + sbase + r * 64 + c4 * 4);
    st[r][c4 * 4 + 0] = v.x; st[r][c4 * 4 + 1] = v.y;
    st[r][c4 * 4 + 2] = v.z; st[r][c4 * 4 + 3] = v.w;
  }
  __syncthreads();
  size_t obase = (size_t)l * 64 * 512 + rt * 64;
#pragma unroll
  for (int i = 0; i < 2; ++i) {
    int idx = tid + i * 256;
    int n = idx >> 3, c = idx & 7;
    uint hw[4], lw[4];
#pragma unroll
    for (int j = 0; j < 4; ++j) hw[j] = pack2(st[c * 8 + 2 * j][n], st[c * 8 + 2 * j + 1][n], lw[j]);
    *(uint4*)(dh + obase + (size_t)n * 512 + c * 8) = make_uint4(hw[0], hw[1], hw[2], hw[3]);
    *(uint4*)(dl + obase + (size_t)n * 512 + c * 8) = make_uint4(lw[0], lw[1], lw[2], lw[3]);
  }
}

__global__ __launch_bounds__(64) void k_gconv(
    const float* __restrict__ x, const float* __restrict__ K3,
    const float* __restrict__ qwl, const float* __restrict__ qbl,
    const float* __restrict__ kwl, const float* __restrict__ kbl,
    const float* __restrict__ vwl, const float* __restrict__ vbl,
    ushort* __restrict__ xqh, ushort* __restrict__ xql,
    ushort* __restrict__ xkh, ushort* __restrict__ xkl, float* __restrict__ xv) {
  __shared__ float sx[64];
  int lane = threadIdx.x;
  size_t bt = blockIdx.x;
  size_t b = bt >> 10, t = bt & 1023;
  float xm = x[bt * 64 + lane];
  sx[lane] = xm;
  __syncthreads();
  float a0 = 0.f, a1 = 0.f, a2 = 0.f;
#pragma unroll 4
  for (int n = 0; n < 64; ++n) {
    float xn = sx[n];
    a0 = fmaf(xn, K3[n * 192 + lane], a0);
    a1 = fmaf(xn, K3[n * 192 + 64 + lane], a1);
    a2 = fmaf(xn, K3[n * 192 + 128 + lane], a2);
  }
#pragma unroll
  for (int hh = 0; hh < HH; ++hh) {
    size_t off = (((size_t)b * HH + hh) * TT + t) * 64 + lane;
    float q = fmaf(qwl[hh * 3 + 0], a0,
              fmaf(qwl[hh * 3 + 1], a1, fmaf(qwl[hh * 3 + 2], a2, qbl[hh] + xm)));
    q = fmaxf(q, 0.f) * 0.015625f;  // fold 1/N into Q
    ushort h_, l_;
    split1(q, h_, l_); xqh[off] = h_; xql[off] = l_;
    float k = fmaf(kwl[hh * 3 + 0], a0,
              fmaf(kwl[hh * 3 + 1], a1, fmaf(kwl[hh * 3 + 2], a2, kbl[hh] + xm)));
    k = fmaxf(k, 0.f);
    split1(k, h_, l_); xkh[off] = h_; xkl[off] = l_;
    float v = fmaf(vwl[hh * 3 + 0], a0,
              fmaf(vwl[hh * 3 + 1], a1, fmaf(vwl[hh * 3 + 2], a2, vbl[hh] + xm)));
    xv[off] = fmaxf(v, 0.f);
  }
}

// ---------- pass A: flash attention, 2-barrier pipelined ----------
__global__ __launch_bounds__(256, 3) void k_attn(
    const ushort* __restrict__ xkh, const ushort* __restrict__ xkl,
    const ushort* __restrict__ xqh, const ushort* __restrict__ xql,
    const ushort* __restrict__ xvTh, const ushort* __restrict__ xvTl,
    float* __restrict__ auv, float* __restrict__ lse) {
  __shared__ ushort sQh[4096], sQl[4096], sVh[4096], sVl[4096], sPh[4096], sPl[4096];
  int tid = threadIdx.x;
  int lane = tid & 63, w = tid >> 6;
  int l15 = lane & 15, g = lane >> 4;
  int nb = gridDim.x, chunk = nb >> 3, bid = blockIdx.x;
  int blk = (bid & 7) * chunk + (bid >> 3);  // XCD swizzle (nb % 8 == 0)
  int bh = blk >> 4, t0 = (blk & 15) << 6;
  size_t bhTT = (size_t)bh * TT;

  // prologue: K tile into (future P) buffers, extract persistent K-frags
  stage_tile(sPh, xkh + (bhTT + t0) * NN, 64, tid);
  stage_tile(sPl, xkl + (bhTT + t0) * NN, 64, tid);
  __syncthreads();
  short8 fKh[2], fKl[2];
#pragma unroll
  for (int ks = 0; ks < 2; ++ks) {
    fKh[ks] = frag(sPh, 16 * w + l15, g + 4 * ks);
    fKl[ks] = frag(sPl, 16 * w + l15, g + 4 * ks);
  }
  uint4 rqh[2], rql[2], rvh[2], rvl[2];
  load2(rqh, xqh + bhTT * NN, 64, tid);
  load2(rql, xql + bhTT * NN, 64, tid);
  load2(rvh, xvTh + bhTT * NN, 1024, tid);
  load2(rvl, xvTl + bhTT * NN, 1024, tid);
  store2(sQh, rqh, tid); store2(sQl, rql, tid);
  store2(sVh, rvh, tid); store2(sVl, rvl, tid);
  __syncthreads();

  float m = -3.0e38f, lsum = 0.f;
  f32x4 O[4];
#pragma unroll
  for (int ct = 0; ct < 4; ++ct)
#pragma unroll
    for (int r = 0; r < 4; ++r) O[ct][r] = 0.f;

  int trow = 16 * w + l15, sw = trow & 7;
  for (int ut = 0; ut < 16; ++ut) {
    int un = (ut + 1) & 15;
    load2(rqh, xqh + (bhTT + un * 64) * NN, 64, tid);
    load2(rql, xql + (bhTT + un * 64) * NN, 64, tid);
    load2(rvh, xvTh + bhTT * NN + un * 64, 1024, tid);
    load2(rvl, xvTl + bhTT * NN + un * 64, 1024, tid);

    __builtin_amdgcn_s_setprio(1);
    f32x4 S[4];
#pragma unroll
    for (int rt = 0; rt < 4; ++rt) {
      f32x4 a = {0.f, 0.f, 0.f, 0.f};
#pragma unroll
      for (int ks = 0; ks < 2; ++ks) {
        short8 aQh = frag(sQh, 16 * rt + l15, g + 4 * ks);
        short8 aQl = frag(sQl, 16 * rt + l15, g + 4 * ks);
        a = MFMA16(aQh, fKh[ks], a);
        a = MFMA16(aQh, fKl[ks], a);
        a = MFMA16(aQl, fKh[ks], a);
      }
      S[rt] = a;
    }
    __builtin_amdgcn_s_setprio(0);

    float tmax = S[0][0];
#pragma unroll
    for (int rt = 0; rt < 4; ++rt)
#pragma unroll
      for (int r = 0; r < 4; ++r) tmax = fmaxf(tmax, S[rt][r]);
    tmax = fmaxf(tmax, __shfl_xor(tmax, 16, 64));
    tmax = fmaxf(tmax, __shfl_xor(tmax, 32, 64));
    float mnew = fmaxf(m, tmax);
    float psum = 0.f;
    uint2 ph[4], plo[4];
#pragma unroll
    for (int rt = 0; rt < 4; ++rt) {
      float p0 = __expf(S[rt][0] - mnew), p1 = __expf(S[rt][1] - mnew);
      float p2 = __expf(S[rt][2] - mnew), p3 = __expf(S[rt][3] - mnew);
      psum += (p0 + p1) + (p2 + p3);
      uint lo0, lo1;
      ph[rt].x = pack2(p0, p1, lo0);
      ph[rt].y = pack2(p2, p3, lo1);
      plo[rt].x = lo0; plo[rt].y = lo1;
    }
    psum += __shfl_xor(psum, 16, 64);
    psum += __shfl_xor(psum, 32, 64);
    if (__ballot(mnew > m)) {
      float f = __expf(m - mnew);
      float fr[4];
#pragma unroll
      for (int r = 0; r < 4; ++r) fr[r] = __shfl(f, (lane & 48) | (4 * g + r), 64);
#pragma unroll
      for (int ct = 0; ct < 4; ++ct)
#pragma unroll
        for (int r = 0; r < 4; ++r) O[ct][r] *= fr[r];
      lsum = lsum * f + psum;
      m = mnew;
    } else {
      lsum += psum;
    }
    // P' write (wave-local rows) then PV — same-wave DS ordering
#pragma unroll
    for (int rt = 0; rt < 4; ++rt) {
      int ch = 2 * rt + (g >> 1);
      int off = trow * 64 + ((ch ^ sw) << 3) + ((g & 1) << 2);
      *(uint2*)(sPh + off) = ph[rt];
      *(uint2*)(sPl + off) = plo[rt];
    }
    asm volatile("s_waitcnt lgkmcnt(0)" ::: "memory");
    __builtin_amdgcn_sched_barrier(0);
    __builtin_amdgcn_s_setprio(1);
#pragma unroll
    for (int ks = 0; ks < 2; ++ks) {
      short8 aPh = frag(sPh, trow, g + 4 * ks);
      short8 aPl = frag(sPl, trow, g + 4 * ks);
#pragma unroll
      for (int ct = 0; ct < 4; ++ct) {
        short8 bVh = frag(sVh, 16 * ct + l15, g + 4 * ks);
        short8 bVl = frag(sVl, 16 * ct + l15, g + 4 * ks);
        O[ct] = MFMA16(aPh, bVh, O[ct]);
        O[ct] = MFMA16(aPh, bVl, O[ct]);
        O[ct] = MFMA16(aPl, bVh, O[ct]);
      }
    }
    __builtin_amdgcn_s_setprio(0);
    __syncthreads();
    store2(sQh, rqh, tid); store2(sQl, rql, tid);
    store2(sVh, rvh, tid); store2(sVl, rvl, tid);
    __syncthreads();
  }
  float il = 1.0f / lsum;
  float ilr[4];
#pragma unroll
  for (int r = 0; r < 4; ++r) ilr[r] = __shfl(il, (lane & 48) | (4 * g + r), 64);
#pragma unroll
  for (int r = 0; r < 4; ++r) {
    size_t row = (bhTT + t0 + 16 * w + 4 * g + r) * NN;
#pragma unroll
    for (int ct = 0; ct < 4; ++ct) auv[row + 16 * ct + l15] = O[ct][r] * ilr[r];
  }
  if (g == 0) lse[bhTT + t0 + 16 * w + l15] = m + __logf(lsum);
}

// ---------- pass B: h1 = relu(P^T @ W1 + b1), 2-barrier pipelined ----------
__global__ __launch_bounds__(256, 3) void k_h1(
    const ushort* __restrict__ xkh, const ushort* __restrict__ xkl,
    const ushort* __restrict__ xqh, const ushort* __restrict__ xql,
    const ushort* __restrict__ w1Th, const ushort* __restrict__ w1Tl,
    const float* __restrict__ lse, const float* __restrict__ b1,
    float* __restrict__ h1) {
  __shared__ ushort sKh[4096], sKl[4096], sWh[4096], sWl[4096], sPh[4096], sPl[4096];
  __shared__ float sL[64];
  int tid = threadIdx.x;
  int lane = tid & 63, w = tid >> 6;
  int l15 = lane & 15, g = lane >> 4;
  int nb = gridDim.x, chunk = nb >> 3, bid = blockIdx.x;
  int blk = (bid & 7) * chunk + (bid >> 3);
  int bh = blk >> 4, h = bh & (HH - 1), a0 = (blk & 15) << 6;
  size_t bhTT = (size_t)bh * TT;
  size_t wbase = (size_t)h * NN * TT;

  stage_tile(sPh, xqh + (bhTT + a0) * NN, 64, tid);
  stage_tile(sPl, xql + (bhTT + a0) * NN, 64, tid);
  __syncthreads();
  short8 fQh[2], fQl[2];
#pragma unroll
  for (int ks = 0; ks < 2; ++ks) {
    fQh[ks] = frag(sPh, 16 * w + l15, g + 4 * ks);
    fQl[ks] = frag(sPl, 16 * w + l15, g + 4 * ks);
  }
  uint4 rkh[2], rkl[2], rwh[2], rwl[2];
  load2(rkh, xkh + bhTT * NN, 64, tid);
  load2(rkl, xkl + bhTT * NN, 64, tid);
  load2(rwh, w1Th + wbase, 1024, tid);
  load2(rwl, w1Tl + wbase, 1024, tid);
  float rl = 0.f;
  if (tid < 64) rl = lse[bhTT + tid];
  store2(sKh, rkh, tid); store2(sKl, rkl, tid);
  store2(sWh, rwh, tid); store2(sWl, rwl, tid);
  if (tid < 64) sL[tid] = rl;
  __syncthreads();

  f32x4 acc[4];
#pragma unroll
  for (int ct = 0; ct < 4; ++ct)
#pragma unroll
    for (int r = 0; r < 4; ++r) acc[ct][r] = 0.f;

  int arow = 16 * w + l15, sw = arow & 7;
  for (int tt = 0; tt < 16; ++tt) {
    int tn = (tt + 1) & 15;
    load2(rkh, xkh + (bhTT + tn * 64) * NN, 64, tid);
    load2(rkl, xkl + (bhTT + tn * 64) * NN, 64, tid);
    load2(rwh, w1Th + wbase + tn * 64, 1024, tid);
    load2(rwl, w1Tl + wbase + tn * 64, 1024, tid);
    if (tid < 64) rl = lse[bhTT + tn * 64 + tid];

    __builtin_amdgcn_s_setprio(1);
    f32x4 S[4];
#pragma unroll
    for (int rt = 0; rt < 4; ++rt) {
      f32x4 a = {0.f, 0.f, 0.f, 0.f};
#pragma unroll
      for (int ks = 0; ks < 2; ++ks) {
        short8 aKh = frag(sKh, 16 * rt + l15, g + 4 * ks);
        short8 aKl = frag(sKl, 16 * rt + l15, g + 4 * ks);
        a = MFMA16(aKh, fQh[ks], a);
        a = MFMA16(aKh, fQl[ks], a);
        a = MFMA16(aKl, fQh[ks], a);
      }
      S[rt] = a;
    }
    __builtin_amdgcn_s_setprio(0);

    uint2 ph[4], plo[4];
#pragma unroll
    for (int rt = 0; rt < 4; ++rt) {
      float p0 = __expf(S[rt][0] - sL[16 * rt + 4 * g + 0]);
      float p1 = __expf(S[rt][1] - sL[16 * rt + 4 * g + 1]);
      float p2 = __expf(S[rt][2] - sL[16 * rt + 4 * g + 2]);
      float p3 = __expf(S[rt][3] - sL[16 * rt + 4 * g + 3]);
      uint lo0, lo1;
      ph[rt].x = pack2(p0, p1, lo0);
      ph[rt].y = pack2(p2, p3, lo1);
      plo[rt].x = lo0; plo[rt].y = lo1;
    }
#pragma unroll
    for (int rt = 0; rt < 4; ++rt) {
      int ch = 2 * rt + (g >> 1);
      int off = arow * 64 + ((ch ^ sw) << 3) + ((g & 1) << 2);
      *(uint2*)(sPh + off) = ph[rt];
      *(uint2*)(sPl + off) = plo[rt];
    }
    asm volatile("s_waitcnt lgkmcnt(0)" ::: "memory");
    __builtin_amdgcn_sched_barrier(0);
    __builtin_amdgcn_s_setprio(1);
#pragma unroll
    for (int ks = 0; ks < 2; ++ks) {
      short8 aPh = frag(sPh, arow, g + 4 * ks);
      short8 aPl = frag(sPl, arow, g + 4 * ks);
#pragma unroll
      for (int ct = 0; ct < 4; ++ct) {
        short8 bWh = frag(sWh, 16 * ct + l15, g + 4 * ks);
        short8 bWl = frag(sWl, 16 * ct + l15, g + 4 * ks);
        acc[ct] = MFMA16(aPh, bWh, acc[ct]);
        acc[ct] = MFMA16(aPh, bWl, acc[ct]);
        acc[ct] = MFMA16(aPl, bWh, acc[ct]);
      }
    }
    __builtin_amdgcn_s_setprio(0);
    __syncthreads();
    store2(sKh, rkh, tid); store2(sKl, rkl, tid);
    store2(sWh, rwh, tid); store2(sWl, rwl, tid);
    if (tid < 64) sL[tid] = rl;
    __syncthreads();
  }
#pragma unroll
  for (int ct = 0; ct < 4; ++ct) {
    float bb = b1[h * 64 + 16 * ct + l15];
#pragma unroll
    for (int r = 0; r < 4; ++r)
      h1[(bhTT + a0 + 16 * w + 4 * g + r) * NN + 16 * ct + l15] =
          fmaxf(acc[ct][r] + bb, 0.f);
  }
}

// h2=relu(h1@W2+b2); g=softmax(h2@W3+b3); ho = g0*auv + g1*xv -> bf16 hi/lo
__global__ __launch_bounds__(256) void k_gate(
    const float* __restrict__ h1, const float* __restrict__ xv,
    const float* __restrict__ W2l, const float* __restrict__ b2l,
    const float* __restrict__ W3l, const float* __restrict__ b3l,
    const float* __restrict__ auv, ushort* __restrict__ hoh,
    ushort* __restrict__ hol) {
  __shared__ float sh1[4][64];
  int tid = threadIdx.x;
  int w = tid >> 6;
  int d = tid & 63;
  size_t blk = blockIdx.x;
  size_t bh = blk >> 8;
  int t = (int)((blk & 255) << 2) + w;
  int h = (int)(bh & (HH - 1));
  size_t rowoff = (bh * TT + (size_t)t) * 64;
  sh1[w][d] = h1[rowoff + d];
  __syncthreads();
  float acc = b2l[h * 64 + d];
  const float* W2 = W2l + (size_t)h * 64 * 64;
#pragma unroll 8
  for (int e = 0; e < 64; ++e) acc = fmaf(sh1[w][e], W2[e * 64 + d], acc);
  acc = fmaxf(acc, 0.f);
  float z0 = acc * W3l[((size_t)h * 64 + d) * 2 + 0];
  float z1 = acc * W3l[((size_t)h * 64 + d) * 2 + 1];
#pragma unroll
  for (int m = 1; m < 64; m <<= 1) {
    z0 += __shfl_xor(z0, m, 64);
    z1 += __shfl_xor(z1, m, 64);
  }
  z0 += b3l[h * 2 + 0];
  z1 += b3l[h * 2 + 1];
  float g0 = 1.0f / (1.0f + __expf(z1 - z0));
  float g1 = 1.0f - g0;
  float ho = g0 * auv[rowoff + d] + g1 * xv[rowoff + d];
  ushort hb, lb;
  split1(ho, hb, lb);
  hoh[rowoff + d] = hb;
  hol[rowoff + d] = lb;
}

// out1 = LN(x + concat_h(ho) @ Wlt) via MFMA over K=512
__global__ __launch_bounds__(256, 3) void k_merge(
    const float* __restrict__ x, const ushort* __restrict__ hoh,
    const ushort* __restrict__ hol, const ushort* __restrict__ wth,
    const ushort* __restrict__ wtl, const float* __restrict__ g1l,
    const float* __restrict__ b1l, float* __restrict__ out1) {
  __shared__ ushort sAh[4096], sAl[4096], sBh[4096], sBl[4096];
  __shared__ float sred[2][64][4];
  __shared__ float sfin[64][2];
  int tid = threadIdx.x;
  int lane = tid & 63, w = tid >> 6;
  int l15 = lane & 15, g = lane >> 4;
  int blk = blockIdx.x;
  int b = blk >> 4, t0 = (blk & 15) << 6;

  uint4 rah[2], ral[2], rbh[2], rbl[2];
  load2(rah, hoh + (((size_t)b * HH + 0) * TT + t0) * NN, 64, tid);
  load2(ral, hol + (((size_t)b * HH + 0) * TT + t0) * NN, 64, tid);
  load2(rbh, wth, 512, tid);
  load2(rbl, wtl, 512, tid);
  store2(sAh, rah, tid); store2(sAl, ral, tid);
  store2(sBh, rbh, tid); store2(sBl, rbl, tid);
  __syncthreads();

  f32x4 acc[4];
#pragma unroll
  for (int rt = 0; rt < 4; ++rt)
#pragma unroll
    for (int r = 0; r < 4; ++r) acc[rt][r] = 0.f;

  for (int h = 0; h < 8; ++h) {
    int hn = (h + 1) & 7;
    load2(rah, hoh + (((size_t)b * HH + hn) * TT + t0) * NN, 64, tid);
    load2(ral, hol + (((size_t)b * HH + hn) * TT + t0) * NN, 64, tid);
    load2(rbh, wth + hn * 64, 512, tid);
    load2(rbl, wtl + hn * 64, 512, tid);
    __builtin_amdgcn_s_setprio(1);
#pragma unroll
    for (int ks = 0; ks < 2; ++ks) {
      short8 bBh = frag(sBh, 16 * w + l15, g + 4 * ks);
      short8 bBl = frag(sBl, 16 * w + l15, g + 4 * ks);
#pragma unroll
      for (int rt = 0; rt < 4; ++rt) {
        short8 aAh = frag(sAh, 16 * rt + l15, g + 4 * ks);
        short8 aAl = frag(sAl, 16 * rt + l15, g + 4 * ks);
        acc[rt] = MFMA16(aAh, bBh, acc[rt]);
        acc[rt] = MFMA16(aAh, bBl, acc[rt]);
        acc[rt] = MFMA16(aAl, bBh, acc[rt]);
      }
    }
    __builtin_amdgcn_s_setprio(0);
    __syncthreads();
    store2(sAh, rah, tid); store2(sAl, ral, tid);
    store2(sBh, rbh, tid); store2(sBl, rbl, tid);
    __syncthreads();
  }
  // epilogue: add x, LayerNorm over the 64 columns
  int mcol = 16 * w + l15;
  float vv[4][4];
#pragma unroll
  for (int rt = 0; rt < 4; ++rt)
#pragma unroll
    for (int r = 0; r < 4; ++r) {
      int row = 16 * rt + 4 * g + r;
      vv[rt][r] = acc[rt][r] + x[((size_t)b * TT + t0 + row) * 64 + mcol];
    }
#pragma unroll
  for (int rt = 0; rt < 4; ++rt)
#pragma unroll
    for (int r = 0; r < 4; ++r) {
      float s1 = vv[rt][r], s2 = vv[rt][r] * vv[rt][r];
#pragma unroll
      for (int mm = 1; mm < 16; mm <<= 1) {
        s1 += __shfl_xor(s1, mm, 64);
        s2 += __shfl_xor(s2, mm, 64);
      }
      if (l15 == 0) {
        int row = 16 * rt + 4 * g + r;
        sred[0][row][w] = s1;
        sred[1][row][w] = s2;
      }
    }
  __syncthreads();
  if (tid < 64) {
    float a1 = sred[0][tid][0] + sred[0][tid][1] + sred[0][tid][2] + sred[0][tid][3];
    float a2 = sred[1][tid][0] + sred[1][tid][1] + sred[1][tid][2] + sred[1][tid][3];
    float mean = a1 * (1.0f / 64.0f);
    float var = a2 * (1.0f / 64.0f) - mean * mean;
    sfin[tid][0] = mean;
    sfin[tid][1] = rsqrtf(var + EPSV);
  }
  __syncthreads();
  float gg = g1l[mcol], bb = b1l[mcol];
#pragma unroll
  for (int rt = 0; rt < 4; ++rt)
#pragma unroll
    for (int r = 0; r < 4; ++r) {
      int row = 16 * rt + 4 * g + r;
      float mean = sfin[row][0], rstd = sfin[row][1];
      out1[((size_t)b * TT + t0 + row) * 64 + mcol] =
          (vv[rt][r] - mean) * rstd * gg + bb;
    }
}

__global__ __launch_bounds__(64) void k_ffn(
    const float* __restrict__ out1, const float* __restrict__ K3sl,
    const float* __restrict__ sclb_l, const float* __restrict__ elWl,
    const float* __restrict__ elbl, const float* __restrict__ g2l,
    const float* __restrict__ b2l, float* __restrict__ xout) {
  __shared__ float so[64], sf[64];
  int lane = threadIdx.x;
  size_t bt = blockIdx.x;
  float o1 = out1[bt * 64 + lane];
  so[lane] = o1;
  __syncthreads();
  float gc = 0.f;
#pragma unroll 8
  for (int n = 0; n < 64; ++n) gc = fmaf(so[n], K3sl[n * 64 + lane], gc);
  float f1 = fmaxf(gc + sclb_l[0] + o1, 0.f);
  sf[lane] = f1;
  __syncthreads();
  float f2 = elbl[lane];
#pragma unroll 8
  for (int e = 0; e < 64; ++e) f2 = fmaf(sf[e], elWl[e * 64 + lane], f2);
  float v = o1 + f2;
  float mu = v;
#pragma unroll
  for (int m = 1; m < 64; m <<= 1) mu += __shfl_xor(mu, m, 64);
  mu *= (1.0f / 64.0f);
  float dd = v - mu;
  float var = dd * dd;
#pragma unroll
  for (int m = 1; m < 64; m <<= 1) var += __shfl_xor(var, m, 64);
  var *= (1.0f / 64.0f);
  xout[bt * 64 + lane] = dd * rsqrtf(var + EPSV) * g2l[lane] + b2l[lane];
}

__global__ __launch_bounds__(256) void k_final(
    const float* __restrict__ x, const float* __restrict__ fW1,
    const float* __restrict__ fb1, const float* __restrict__ fW2,
    const float* __restrict__ fb2, float* __restrict__ out) {
  __shared__ float pl[4][64];
  int tid = threadIdx.x;
  int lane = tid & 63, w = tid >> 6;
  size_t b = blockIdx.x;
  float s = 0.f;
  for (int t = 256 * w; t < 256 * w + 256; ++t) s += x[(b * TT + t) * 64 + lane];
  pl[w][lane] = s;
  __syncthreads();
  if (tid < 64) pl[0][tid] = (pl[0][tid] + pl[1][tid] + pl[2][tid] + pl[3][tid]) * (1.0f / TT);
  __syncthreads();
  if (tid < 64) {
    float hv = 0.f;
    if (lane < 32) {
      hv = fb1[lane];
#pragma unroll 8
      for (int n = 0; n < 64; ++n) hv = fmaf(pl[0][n], fW1[n * 32 + lane], hv);
      hv = fmaxf(hv, 0.f) * fW2[lane];
    }
#pragma unroll
    for (int m = 1; m < 64; m <<= 1) hv += __shfl_xor(hv, m, 64);
    if (lane == 0) out[b] = hv + fb2[0];
  }
}

extern "C" void kernel_launch(void* const* d_in, const int* in_sizes, int n_in,
                              void* d_out, int out_size, void* d_ws, size_t ws_size,
                              hipStream_t stream) {
  const float* inputs = (const float*)d_in[0];
  const float* pos_emb = (const float*)d_in[1];
  const float* K3 = (const float*)d_in[2];
  const float* qw = (const float*)d_in[3];
  const float* qb = (const float*)d_in[4];
  const float* kw = (const float*)d_in[5];
  const float* kb = (const float*)d_in[6];
  const float* vw = (const float*)d_in[7];
  const float* vb = (const float*)d_in[8];
  const float* tqW1 = (const float*)d_in[9];
  const float* tqb1 = (const float*)d_in[10];
  const float* tqW2 = (const float*)d_in[11];
  const float* tqb2 = (const float*)d_in[12];
  const float* tqW3 = (const float*)d_in[13];
  const float* tqb3 = (const float*)d_in[14];
  const float* Wlt = (const float*)d_in[15];
  const float* ln1g = (const float*)d_in[16];
  const float* ln1b = (const float*)d_in[17];
  const float* ln2g = (const float*)d_in[18];
  const float* ln2b = (const float*)d_in[19];
  const float* sclw = (const float*)d_in[20];
  const float* sclb = (const float*)d_in[21];
  const float* elW = (const float*)d_in[22];
  const float* elb = (const float*)d_in[23];
  const float* fW1 = (const float*)d_in[24];
  const float* fb1 = (const float*)d_in[25];
  const float* fW2 = (const float*)d_in[26];
  const float* fb2 = (const float*)d_in[27];
  float* out = (float*)d_out;
  float* ws_f = (float*)d_ws;

  const size_t TN = (size_t)TT * NN;
  const size_t HTN = (size_t)HH * TT * NN;
  const size_t W1T_ELEMS = (size_t)LL * HH * NN * TT;  // ushorts
  const size_t WLT_ELEMS = (size_t)LL * 64 * 512;      // ushorts

  float* K3s = ws_f;
  ushort* w1Th = (ushort*)(ws_f + 2 * 4096);
  ushort* w1Tl = w1Th + W1T_ELEMS;
  ushort* wth = w1Tl + W1T_ELEMS;
  ushort* wtl = wth + WLT_ELEMS;
  const size_t base = 2 * 4096 + W1T_ELEMS + WLT_ELEMS;  // words

  for (int l = 0; l < LL; ++l)
    k_k3s<<<16, 256, 0, stream>>>(K3, sclw + l * KSS, K3s + (size_t)l * 4096);
  k_tsplit<<<LL * HH * 16, 256, 0, stream>>>(tqW1, w1Th, w1Tl);
  k_tsplitW<<<LL * 8, 256, 0, stream>>>(Wlt, wth, wtl);

  // per-batch words: f32 {x,out1, xv,auv,h1, lse} + ush {q h/l, k h/l, vT h/l, ho h/l}
  const size_t per_b = 2 * TN + 3 * HTN + (size_t)HH * TT + 4 * HTN;
  size_t avail = ws_size / sizeof(float);
  avail = (avail > base) ? avail - base : 0;
  int Bc = (int)(avail / per_b);
  if (Bc > BB) Bc = BB;
  if (Bc < 1) Bc = 1;

  for (int b0 = 0; b0 < BB; b0 += Bc) {
    int bc = (BB - b0 < Bc) ? (BB - b0) : Bc;
    float* x = ws_f + base;
    float* out1 = x + (size_t)bc * TN;
    float* xv = out1 + (size_t)bc * TN;
    float* auv = xv + (size_t)bc * HTN;
    float* h1 = auv + (size_t)bc * HTN;
    float* lseb = h1 + (size_t)bc * HTN;
    ushort* xqh = (ushort*)(lseb + (size_t)bc * HH * TT);
    ushort* xql = xqh + (size_t)bc * HTN;
    ushort* xkh = xql + (size_t)bc * HTN;
    ushort* xkl = xkh + (size_t)bc * HTN;
    ushort* xvTh = xkl + (size_t)bc * HTN;
    ushort* xvTl = xvTh + (size_t)bc * HTN;
    ushort* hoh = xvTl + (size_t)bc * HTN;
    ushort* hol = hoh + (size_t)bc * HTN;

    int total = bc * (int)TN;
    k_addpos<<<(total + 255) / 256, 256, 0, stream>>>(inputs + (size_t)b0 * TN, pos_emb, x,
                                                      total);
    for (int l = 0; l < LL; ++l) {
      k_gconv<<<bc * TT, 64, 0, stream>>>(x, K3, qw + l * HH * KSS, qb + l * HH,
                                          kw + l * HH * KSS, kb + l * HH,
                                          vw + l * HH * KSS, vb + l * HH,
                                          xqh, xql, xkh, xkl, xv);
      k_tsplit<<<bc * HH * 16, 256, 0, stream>>>(xv, xvTh, xvTl);
      k_attn<<<bc * HH * 16, 256, 0, stream>>>(xkh, xkl, xqh, xql, xvTh, xvTl, auv, lseb);
      k_h1<<<bc * HH * 16, 256, 0, stream>>>(
          xkh, xkl, xqh, xql, w1Th + (size_t)l * HH * NN * TT,
          w1Tl + (size_t)l * HH * NN * TT, lseb, tqb1 + l * HH * DD1, h1);
      k_gate<<<bc * HH * (TT / 4), 256, 0, stream>>>(
          h1, xv, tqW2 + (size_t)l * HH * DD1 * DD1, tqb2 + l * HH * DD1,
          tqW3 + (size_t)l * HH * DD1 * 2, tqb3 + l * HH * 2, auv, hoh, hol);
      k_merge<<<bc * 16, 256, 0, stream>>>(x, hoh, hol, wth + (size_t)l * 64 * 512,
                                           wtl + (size_t)l * 64 * 512, ln1g + l * NN,
                                           ln1b + l * NN, out1);
      k_ffn<<<bc * TT, 64, 0, stream>>>(out1, K3s + (size_t)l * 4096, sclb + l,
                                        elW + (size_t)l * NN * NN, elb + l * NN,
                                        ln2g + l * NN, ln2b + l * NN, x);
    }
    k_final<<<bc, 256, 0, stream>>>(x, fW1, fb1, fW2, fb2, out + b0);
  }
}

// Round 4
// 463.281 us; speedup vs baseline: 1.8462x; 1.8462x over previous
//
#include <hip/hip_runtime.h>

typedef __attribute__((ext_vector_type(8))) short short8;
typedef __attribute__((ext_vector_type(4))) float f32x4;

#define BB 8
#define TT 1024
#define NN 64
#define HH 8
#define LL 2
#define KSS 3
#define DD1 64
#define EPSV 1e-6f

#define MFMA16(a, b, c) __builtin_amdgcn_mfma_f32_16x16x32_bf16(a, b, c, 0, 0, 0)
#define BAR() __builtin_amdgcn_s_barrier()
#define WAIT_VM8() asm volatile("s_waitcnt vmcnt(8)" ::: "memory")
#define WAIT_VM0() asm volatile("s_waitcnt vmcnt(0)" ::: "memory")
#define WAIT_LGKM0() asm volatile("s_waitcnt lgkmcnt(0)" ::: "memory")

// ---- truncation-based hi/lo bf16 split (hi error lands exactly in lo) ----
__device__ __forceinline__ void split1(float x, ushort& hi, ushort& lo) {
  uint u = __float_as_uint(x);
  hi = (ushort)(u >> 16);
  float hf = __uint_as_float(u & 0xffff0000u);
  lo = (ushort)(__float_as_uint(x - hf) >> 16);
}
__device__ __forceinline__ uint pack2(float a, float b, uint& lo) {
  uint ua = __float_as_uint(a), ub = __float_as_uint(b);
  float ra = __uint_as_float(ua & 0xffff0000u);
  float rb = __uint_as_float(ub & 0xffff0000u);
  lo = (__float_as_uint(a - ra) >> 16) | (__float_as_uint(b - rb) & 0xffff0000u);
  return (ua >> 16) | (ub & 0xffff0000u);
}

// ---- async global->LDS staging of a 64x64 bf16 tile, swizzled via source ----
__device__ __forceinline__ void gl2lds16(const ushort* g, ushort* l) {
  __builtin_amdgcn_global_load_lds(
      (const __attribute__((address_space(1))) void*)g,
      (__attribute__((address_space(3))) void*)l, 16, 0, 0);
}
// LDS[row][ch] = G[row][ch ^ (row&7)] (16B chunks); 2 gl_lds per wave
__device__ __forceinline__ void stage_async(ushort* __restrict__ s,
                                            const ushort* __restrict__ g,
                                            int stride, int tid) {
  int w = tid >> 6;
  int sub = (tid & 63) >> 3, c = tid & 7;
#pragma unroll
  for (int i = 0; i < 2; ++i) {
    int rb = (i * 4 + w) * 8;
    gl2lds16(g + (size_t)(rb + sub) * stride + ((c ^ sub) << 3), s + rb * 64);
  }
}
__device__ __forceinline__ short8 frag(const ushort* __restrict__ s, int row, int ch) {
  return *(const short8*)(s + row * 64 + ((ch ^ (row & 7)) << 3));
}

// ---------- small kernels ----------

__global__ void k_addpos(const float* __restrict__ in, const float* __restrict__ pe,
                         float* __restrict__ x, int total) {
  int idx = blockIdx.x * 256 + threadIdx.x;
  if (idx < total) {
    int tn = idx & (TT * NN - 1);
    x[idx] = in[idx] + pe[tn];
  }
}

__global__ void k_k3s(const float* __restrict__ K3, const float* __restrict__ sclwl,
                      float* __restrict__ K3s) {
  int idx = blockIdx.x * 256 + threadIdx.x;
  int n = idx >> 6, m = idx & 63;
  K3s[idx] = K3[n * 192 + m] * sclwl[0] + K3[n * 192 + 64 + m] * sclwl[1] +
             K3[n * 192 + 128 + m] * sclwl[2];
}

// transpose+split: src [mat][1024][64] f32 -> dh/dl [mat][64][1024] bf16 hi/lo
__global__ __launch_bounds__(256) void k_tsplit(const float* __restrict__ src,
                                                ushort* __restrict__ dh,
                                                ushort* __restrict__ dl) {
  __shared__ float st[64][65];
  int blk = blockIdx.x;
  int mat = blk >> 4, rt = blk & 15;
  int tid = threadIdx.x;
  size_t sbase = ((size_t)mat * TT + rt * 64) * 64;
#pragma unroll
  for (int i = 0; i < 4; ++i) {
    int idx = tid + i * 256;
    int r = idx >> 4, c4 = idx & 15;
    float4 v = *(const float4*)(src + sbase + r * 64 + c4 * 4);
    st[r][c4 * 4 + 0] = v.x; st[r][c4 * 4 + 1] = v.y;
    st[r][c4 * 4 + 2] = v.z; st[r][c4 * 4 + 3] = v.w;
  }
  __syncthreads();
  size_t obase = (size_t)mat * (64 * (size_t)TT) + rt * 64;
#pragma unroll
  for (int i = 0; i < 2; ++i) {
    int idx = tid + i * 256;
    int n = idx >> 3, c = idx & 7;
    uint hw[4], lw[4];
#pragma unroll
    for (int j = 0; j < 4; ++j) hw[j] = pack2(st[c * 8 + 2 * j][n], st[c * 8 + 2 * j + 1][n], lw[j]);
    *(uint4*)(dh + obase + (size_t)n * TT + c * 8) = make_uint4(hw[0], hw[1], hw[2], hw[3]);
    *(uint4*)(dl + obase + (size_t)n * TT + c * 8) = make_uint4(lw[0], lw[1], lw[2], lw[3]);
  }
}

// transpose+split Wlt: [L][512][64] f32 -> [L][64][512] bf16 hi/lo
__global__ __launch_bounds__(256) void k_tsplitW(const float* __restrict__ Wlt,
                                                 ushort* __restrict__ dh,
                                                 ushort* __restrict__ dl) {
  __shared__ float st[64][65];
  int blk = blockIdx.x;
  int l = blk >> 3, rt = blk & 7;
  int tid = threadIdx.x;
  size_t sbase = ((size_t)l * 512 + rt * 64) * 64;
#pragma unroll
  for (int i = 0; i < 4; ++i) {
    int idx = tid + i * 256;
    int r = idx >> 4, c4 = idx & 15;
    float4 v = *(const float4*)(Wlt + sbase + r * 64 + c4 * 4);
    st[r][c4 * 4 + 0] = v.x; st[r][c4 * 4 + 1] = v.y;
    st[r][c4 * 4 + 2] = v.z; st[r][c4 * 4 + 3] = v.w;
  }
  __syncthreads();
  size_t obase = (size_t)l * 64 * 512 + rt * 64;
#pragma unroll
  for (int i = 0; i < 2; ++i) {
    int idx = tid + i * 256;
    int n = idx >> 3, c = idx & 7;
    uint hw[4], lw[4];
#pragma unroll
    for (int j = 0; j < 4; ++j) hw[j] = pack2(st[c * 8 + 2 * j][n], st[c * 8 + 2 * j + 1][n], lw[j]);
    *(uint4*)(dh + obase + (size_t)n * 512 + c * 8) = make_uint4(hw[0], hw[1], hw[2], hw[3]);
    *(uint4*)(dl + obase + (size_t)n * 512 + c * 8) = make_uint4(lw[0], lw[1], lw[2], lw[3]);
  }
}

__global__ __launch_bounds__(64) void k_gconv(
    const float* __restrict__ x, const float* __restrict__ K3,
    const float* __restrict__ qwl, const float* __restrict__ qbl,
    const float* __restrict__ kwl, const float* __restrict__ kbl,
    const float* __restrict__ vwl, const float* __restrict__ vbl,
    ushort* __restrict__ xqh, ushort* __restrict__ xql,
    ushort* __restrict__ xkh, ushort* __restrict__ xkl, float* __restrict__ xv) {
  __shared__ float sx[64];
  int lane = threadIdx.x;
  size_t bt = blockIdx.x;
  size_t b = bt >> 10, t = bt & 1023;
  float xm = x[bt * 64 + lane];
  sx[lane] = xm;
  __syncthreads();
  float a0 = 0.f, a1 = 0.f, a2 = 0.f;
#pragma unroll 4
  for (int n = 0; n < 64; ++n) {
    float xn = sx[n];
    a0 = fmaf(xn, K3[n * 192 + lane], a0);
    a1 = fmaf(xn, K3[n * 192 + 64 + lane], a1);
    a2 = fmaf(xn, K3[n * 192 + 128 + lane], a2);
  }
#pragma unroll
  for (int hh = 0; hh < HH; ++hh) {
    size_t off = (((size_t)b * HH + hh) * TT + t) * 64 + lane;
    float q = fmaf(qwl[hh * 3 + 0], a0,
              fmaf(qwl[hh * 3 + 1], a1, fmaf(qwl[hh * 3 + 2], a2, qbl[hh] + xm)));
    q = fmaxf(q, 0.f) * 0.015625f;  // fold 1/N into Q
    ushort h_, l_;
    split1(q, h_, l_); xqh[off] = h_; xql[off] = l_;
    float k = fmaf(kwl[hh * 3 + 0], a0,
              fmaf(kwl[hh * 3 + 1], a1, fmaf(kwl[hh * 3 + 2], a2, kbl[hh] + xm)));
    k = fmaxf(k, 0.f);
    split1(k, h_, l_); xkh[off] = h_; xkl[off] = l_;
    float v = fmaf(vwl[hh * 3 + 0], a0,
              fmaf(vwl[hh * 3 + 1], a1, fmaf(vwl[hh * 3 + 2], a2, vbl[hh] + xm)));
    xv[off] = fmaxf(v, 0.f);
  }
}

// ---------- pass A: flash attention, async dbuf staging + counted vmcnt ----------
__global__ __launch_bounds__(256, 2) void k_attn(
    const ushort* __restrict__ xkh, const ushort* __restrict__ xkl,
    const ushort* __restrict__ xqh, const ushort* __restrict__ xql,
    const ushort* __restrict__ xvTh, const ushort* __restrict__ xvTl,
    float* __restrict__ auv, float* __restrict__ lse) {
  __shared__ ushort sQh[2][4096], sQl[2][4096], sVh[2][4096], sVl[2][4096];
  __shared__ ushort sPh[4096], sPl[4096];
  int tid = threadIdx.x;
  int lane = tid & 63, w = tid >> 6;
  int l15 = lane & 15, g = lane >> 4;
  int nb = gridDim.x, chunk = nb >> 3, bid = blockIdx.x;
  int blk = (bid & 7) * chunk + (bid >> 3);  // XCD swizzle (nb % 8 == 0)
  int bh = blk >> 4, t0 = (blk & 15) << 6;
  size_t bhTT = (size_t)bh * TT;

  // prologue: K tile -> buf1 of Q (4 instr), tile0 -> buf0 (8 instr)
  stage_async(sQh[1], xkh + (bhTT + t0) * NN, 64, tid);
  stage_async(sQl[1], xkl + (bhTT + t0) * NN, 64, tid);
  stage_async(sQh[0], xqh + bhTT * NN, 64, tid);
  stage_async(sQl[0], xql + bhTT * NN, 64, tid);
  stage_async(sVh[0], xvTh + bhTT * NN, 1024, tid);
  stage_async(sVl[0], xvTl + bhTT * NN, 1024, tid);
  WAIT_VM8();  // K landed (tile0's 8 may remain in flight)
  BAR();
  short8 fKh[2], fKl[2];
#pragma unroll
  for (int ks = 0; ks < 2; ++ks) {
    fKh[ks] = frag(sQh[1], 16 * w + l15, g + 4 * ks);
    fKl[ks] = frag(sQl[1], 16 * w + l15, g + 4 * ks);
  }
  WAIT_LGKM0();
  BAR();  // all waves done reading K region
  stage_async(sQh[1], xqh + (bhTT + 64) * NN, 64, tid);
  stage_async(sQl[1], xql + (bhTT + 64) * NN, 64, tid);
  stage_async(sVh[1], xvTh + bhTT * NN + 64, 1024, tid);
  stage_async(sVl[1], xvTl + bhTT * NN + 64, 1024, tid);

  float m = -3.0e38f, lsum = 0.f;
  f32x4 O[4];
#pragma unroll
  for (int ct = 0; ct < 4; ++ct)
#pragma unroll
    for (int r = 0; r < 4; ++r) O[ct][r] = 0.f;

  int trow = 16 * w + l15, swz = trow & 7;
  for (int ut = 0; ut < 16; ++ut) {
    int cur = ut & 1;
    if (ut < 15) WAIT_VM8(); else WAIT_VM0();
    BAR();
    const ushort* cQh = sQh[cur];
    const ushort* cQl = sQl[cur];
    const ushort* cVh = sVh[cur];
    const ushort* cVl = sVl[cur];

    __builtin_amdgcn_s_setprio(1);
    f32x4 S[4];
#pragma unroll
    for (int rt = 0; rt < 4; ++rt) {
      f32x4 a = {0.f, 0.f, 0.f, 0.f};
#pragma unroll
      for (int ks = 0; ks < 2; ++ks) {
        short8 aQh = frag(cQh, 16 * rt + l15, g + 4 * ks);
        short8 aQl = frag(cQl, 16 * rt + l15, g + 4 * ks);
        a = MFMA16(aQh, fKh[ks], a);
        a = MFMA16(aQh, fKl[ks], a);
        a = MFMA16(aQl, fKh[ks], a);
      }
      S[rt] = a;
    }
    __builtin_amdgcn_s_setprio(0);

    float tmax = S[0][0];
#pragma unroll
    for (int rt = 0; rt < 4; ++rt)
#pragma unroll
      for (int r = 0; r < 4; ++r) tmax = fmaxf(tmax, S[rt][r]);
    tmax = fmaxf(tmax, __shfl_xor(tmax, 16, 64));
    tmax = fmaxf(tmax, __shfl_xor(tmax, 32, 64));
    if (__ballot(tmax > m + 4.f)) {  // T13 deferred rescale
      float mnew = fmaxf(m, tmax);
      float f = __expf(m - mnew);
      float fr[4];
#pragma unroll
      for (int r = 0; r < 4; ++r) fr[r] = __shfl(f, (lane & 48) | (4 * g + r), 64);
#pragma unroll
      for (int ct = 0; ct < 4; ++ct)
#pragma unroll
        for (int r = 0; r < 4; ++r) O[ct][r] *= fr[r];
      lsum *= f;
      m = mnew;
    }
    float psum = 0.f;
    uint2 ph[4], plo[4];
#pragma unroll
    for (int rt = 0; rt < 4; ++rt) {
      float p0 = __expf(S[rt][0] - m), p1 = __expf(S[rt][1] - m);
      float p2 = __expf(S[rt][2] - m), p3 = __expf(S[rt][3] - m);
      psum += (p0 + p1) + (p2 + p3);
      uint lo0, lo1;
      ph[rt].x = pack2(p0, p1, lo0);
      ph[rt].y = pack2(p2, p3, lo1);
      plo[rt].x = lo0; plo[rt].y = lo1;
    }
    psum += __shfl_xor(psum, 16, 64);
    psum += __shfl_xor(psum, 32, 64);
    lsum += psum;
    // P' write (wave-local rows) then PV — same-wave DS ordering
#pragma unroll
    for (int rt = 0; rt < 4; ++rt) {
      int ch = 2 * rt + (g >> 1);
      int off = trow * 64 + ((ch ^ swz) << 3) + ((g & 1) << 2);
      *(uint2*)(sPh + off) = ph[rt];
      *(uint2*)(sPl + off) = plo[rt];
    }
    WAIT_LGKM0();
    __builtin_amdgcn_sched_barrier(0);
    __builtin_amdgcn_s_setprio(1);
#pragma unroll
    for (int ks = 0; ks < 2; ++ks) {
      short8 aPh = frag(sPh, trow, g + 4 * ks);
      short8 aPl = frag(sPl, trow, g + 4 * ks);
#pragma unroll
      for (int ct = 0; ct < 4; ++ct) {
        short8 bVh = frag(cVh, 16 * ct + l15, g + 4 * ks);
        short8 bVl = frag(cVl, 16 * ct + l15, g + 4 * ks);
        O[ct] = MFMA16(aPh, bVh, O[ct]);
        O[ct] = MFMA16(aPh, bVl, O[ct]);
        O[ct] = MFMA16(aPl, bVh, O[ct]);
      }
    }
    __builtin_amdgcn_s_setprio(0);
    WAIT_LGKM0();
    BAR();  // all waves done reading buf[cur]
    if (ut < 14) {
      int tn = ut + 2;
      stage_async(sQh[cur], xqh + (bhTT + tn * 64) * NN, 64, tid);
      stage_async(sQl[cur], xql + (bhTT + tn * 64) * NN, 64, tid);
      stage_async(sVh[cur], xvTh + bhTT * NN + tn * 64, 1024, tid);
      stage_async(sVl[cur], xvTl + bhTT * NN + tn * 64, 1024, tid);
    }
  }
  float il = 1.0f / lsum;
  float ilr[4];
#pragma unroll
  for (int r = 0; r < 4; ++r) ilr[r] = __shfl(il, (lane & 48) | (4 * g + r), 64);
#pragma unroll
  for (int r = 0; r < 4; ++r) {
    size_t row = (bhTT + t0 + 16 * w + 4 * g + r) * NN;
#pragma unroll
    for (int ct = 0; ct < 4; ++ct) auv[row + 16 * ct + l15] = O[ct][r] * ilr[r];
  }
  if (g == 0) lse[bhTT + t0 + 16 * w + l15] = m + __logf(lsum);
}

// ---------- pass B: h1 = relu(P^T @ W1 + b1), async dbuf staging ----------
__global__ __launch_bounds__(256, 2) void k_h1(
    const ushort* __restrict__ xkh, const ushort* __restrict__ xkl,
    const ushort* __restrict__ xqh, const ushort* __restrict__ xql,
    const ushort* __restrict__ w1Th, const ushort* __restrict__ w1Tl,
    const float* __restrict__ lse, const float* __restrict__ b1,
    float* __restrict__ h1) {
  __shared__ ushort sKh[2][4096], sKl[2][4096], sWh[2][4096], sWl[2][4096];
  __shared__ ushort sPh[4096], sPl[4096];
  int tid = threadIdx.x;
  int lane = tid & 63, w = tid >> 6;
  int l15 = lane & 15, g = lane >> 4;
  int nb = gridDim.x, chunk = nb >> 3, bid = blockIdx.x;
  int blk = (bid & 7) * chunk + (bid >> 3);
  int bh = blk >> 4, h = bh & (HH - 1), a0 = (blk & 15) << 6;
  size_t bhTT = (size_t)bh * TT;
  size_t wbase = (size_t)h * NN * TT;

  stage_async(sKh[1], xqh + (bhTT + a0) * NN, 64, tid);  // Q tile for frags
  stage_async(sKl[1], xql + (bhTT + a0) * NN, 64, tid);
  stage_async(sKh[0], xkh + bhTT * NN, 64, tid);         // tile0
  stage_async(sKl[0], xkl + bhTT * NN, 64, tid);
  stage_async(sWh[0], w1Th + wbase, 1024, tid);
  stage_async(sWl[0], w1Tl + wbase, 1024, tid);
  WAIT_VM8();
  BAR();
  short8 fQh[2], fQl[2];
#pragma unroll
  for (int ks = 0; ks < 2; ++ks) {
    fQh[ks] = frag(sKh[1], 16 * w + l15, g + 4 * ks);
    fQl[ks] = frag(sKl[1], 16 * w + l15, g + 4 * ks);
  }
  WAIT_LGKM0();
  BAR();
  stage_async(sKh[1], xkh + (bhTT + 64) * NN, 64, tid);  // tile1
  stage_async(sKl[1], xkl + (bhTT + 64) * NN, 64, tid);
  stage_async(sWh[1], w1Th + wbase + 64, 1024, tid);
  stage_async(sWl[1], w1Tl + wbase + 64, 1024, tid);

  f32x4 acc[4];
#pragma unroll
  for (int ct = 0; ct < 4; ++ct)
#pragma unroll
    for (int r = 0; r < 4; ++r) acc[ct][r] = 0.f;

  int arow = 16 * w + l15, swz = arow & 7;
  for (int tt = 0; tt < 16; ++tt) {
    int cur = tt & 1;
    if (tt < 15) WAIT_VM8(); else WAIT_VM0();
    BAR();
    const ushort* cKh = sKh[cur];
    const ushort* cKl = sKl[cur];
    const ushort* cWh = sWh[cur];
    const ushort* cWl = sWl[cur];
    // lse for this tile's t-rows (L2-hot, hidden under QK MFMAs)
    f32x4 lsev[4];
#pragma unroll
    for (int rt = 0; rt < 4; ++rt)
      lsev[rt] = *(const f32x4*)(lse + bhTT + tt * 64 + 16 * rt + 4 * g);

    __builtin_amdgcn_s_setprio(1);
    f32x4 S[4];
#pragma unroll
    for (int rt = 0; rt < 4; ++rt) {
      f32x4 a = {0.f, 0.f, 0.f, 0.f};
#pragma unroll
      for (int ks = 0; ks < 2; ++ks) {
        short8 aKh = frag(cKh, 16 * rt + l15, g + 4 * ks);
        short8 aKl = frag(cKl, 16 * rt + l15, g + 4 * ks);
        a = MFMA16(aKh, fQh[ks], a);
        a = MFMA16(aKh, fQl[ks], a);
        a = MFMA16(aKl, fQh[ks], a);
      }
      S[rt] = a;
    }
    __builtin_amdgcn_s_setprio(0);

    uint2 ph[4], plo[4];
#pragma unroll
    for (int rt = 0; rt < 4; ++rt) {
      float p0 = __expf(S[rt][0] - lsev[rt][0]);
      float p1 = __expf(S[rt][1] - lsev[rt][1]);
      float p2 = __expf(S[rt][2] - lsev[rt][2]);
      float p3 = __expf(S[rt][3] - lsev[rt][3]);
      uint lo0, lo1;
      ph[rt].x = pack2(p0, p1, lo0);
      ph[rt].y = pack2(p2, p3, lo1);
      plo[rt].x = lo0; plo[rt].y = lo1;
    }
#pragma unroll
    for (int rt = 0; rt < 4; ++rt) {
      int ch = 2 * rt + (g >> 1);
      int off = arow * 64 + ((ch ^ swz) << 3) + ((g & 1) << 2);
      *(uint2*)(sPh + off) = ph[rt];
      *(uint2*)(sPl + off) = plo[rt];
    }
    WAIT_LGKM0();
    __builtin_amdgcn_sched_barrier(0);
    __builtin_amdgcn_s_setprio(1);
#pragma unroll
    for (int ks = 0; ks < 2; ++ks) {
      short8 aPh = frag(sPh, arow, g + 4 * ks);
      short8 aPl = frag(sPl, arow, g + 4 * ks);
#pragma unroll
      for (int ct = 0; ct < 4; ++ct) {
        short8 bWh = frag(cWh, 16 * ct + l15, g + 4 * ks);
        short8 bWl = frag(cWl, 16 * ct + l15, g + 4 * ks);
        acc[ct] = MFMA16(aPh, bWh, acc[ct]);
        acc[ct] = MFMA16(aPh, bWl, acc[ct]);
        acc[ct] = MFMA16(aPl, bWh, acc[ct]);
      }
    }
    __builtin_amdgcn_s_setprio(0);
    WAIT_LGKM0();
    BAR();
    if (tt < 14) {
      int tn = tt + 2;
      stage_async(sKh[cur], xkh + (bhTT + tn * 64) * NN, 64, tid);
      stage_async(sKl[cur], xkl + (bhTT + tn * 64) * NN, 64, tid);
      stage_async(sWh[cur], w1Th + wbase + tn * 64, 1024, tid);
      stage_async(sWl[cur], w1Tl + wbase + tn * 64, 1024, tid);
    }
  }
#pragma unroll
  for (int ct = 0; ct < 4; ++ct) {
    float bb = b1[h * 64 + 16 * ct + l15];
#pragma unroll
    for (int r = 0; r < 4; ++r)
      h1[(bhTT + a0 + 16 * w + 4 * g + r) * NN + 16 * ct + l15] =
          fmaxf(acc[ct][r] + bb, 0.f);
  }
}

// h2=relu(h1@W2+b2); g=softmax(h2@W3+b3); ho = g0*auv + g1*xv -> bf16 hi/lo
__global__ __launch_bounds__(256) void k_gate(
    const float* __restrict__ h1, const float* __restrict__ xv,
    const float* __restrict__ W2l, const float* __restrict__ b2l,
    const float* __restrict__ W3l, const float* __restrict__ b3l,
    const float* __restrict__ auv, ushort* __restrict__ hoh,
    ushort* __restrict__ hol) {
  __shared__ float sh1[4][64];
  int tid = threadIdx.x;
  int w = tid >> 6;
  int d = tid & 63;
  size_t blk = blockIdx.x;
  size_t bh = blk >> 8;
  int t = (int)((blk & 255) << 2) + w;
  int h = (int)(bh & (HH - 1));
  size_t rowoff = (bh * TT + (size_t)t) * 64;
  sh1[w][d] = h1[rowoff + d];
  __syncthreads();
  float acc = b2l[h * 64 + d];
  const float* W2 = W2l + (size_t)h * 64 * 64;
#pragma unroll 8
  for (int e = 0; e < 64; ++e) acc = fmaf(sh1[w][e], W2[e * 64 + d], acc);
  acc = fmaxf(acc, 0.f);
  float z0 = acc * W3l[((size_t)h * 64 + d) * 2 + 0];
  float z1 = acc * W3l[((size_t)h * 64 + d) * 2 + 1];
#pragma unroll
  for (int m = 1; m < 64; m <<= 1) {
    z0 += __shfl_xor(z0, m, 64);
    z1 += __shfl_xor(z1, m, 64);
  }
  z0 += b3l[h * 2 + 0];
  z1 += b3l[h * 2 + 1];
  float g0 = 1.0f / (1.0f + __expf(z1 - z0));
  float g1 = 1.0f - g0;
  float ho = g0 * auv[rowoff + d] + g1 * xv[rowoff + d];
  ushort hb, lb;
  split1(ho, hb, lb);
  hoh[rowoff + d] = hb;
  hol[rowoff + d] = lb;
}

// out1 = LN(x + concat_h(ho) @ Wlt) via MFMA over K=512, async dbuf staging
__global__ __launch_bounds__(256, 2) void k_merge(
    const float* __restrict__ x, const ushort* __restrict__ hoh,
    const ushort* __restrict__ hol, const ushort* __restrict__ wth,
    const ushort* __restrict__ wtl, const float* __restrict__ g1l,
    const float* __restrict__ b1l, float* __restrict__ out1) {
  __shared__ ushort sAh[2][4096], sAl[2][4096], sBh[2][4096], sBl[2][4096];
  __shared__ float sred[2][64][4];
  __shared__ float sfin[64][2];
  int tid = threadIdx.x;
  int lane = tid & 63, w = tid >> 6;
  int l15 = lane & 15, g = lane >> 4;
  int blk = blockIdx.x;
  int b = blk >> 4, t0 = (blk & 15) << 6;

  {
    size_t ab0 = (((size_t)b * HH + 0) * TT + t0) * NN;
    size_t ab1 = (((size_t)b * HH + 1) * TT + t0) * NN;
    stage_async(sAh[0], hoh + ab0, 64, tid);
    stage_async(sAl[0], hol + ab0, 64, tid);
    stage_async(sBh[0], wth, 512, tid);
    stage_async(sBl[0], wtl, 512, tid);
    stage_async(sAh[1], hoh + ab1, 64, tid);
    stage_async(sAl[1], hol + ab1, 64, tid);
    stage_async(sBh[1], wth + 64, 512, tid);
    stage_async(sBl[1], wtl + 64, 512, tid);
  }

  f32x4 acc[4];
#pragma unroll
  for (int rt = 0; rt < 4; ++rt)
#pragma unroll
    for (int r = 0; r < 4; ++r) acc[rt][r] = 0.f;

  for (int h = 0; h < 8; ++h) {
    int cur = h & 1;
    if (h < 7) WAIT_VM8(); else WAIT_VM0();
    BAR();
    __builtin_amdgcn_s_setprio(1);
#pragma unroll
    for (int ks = 0; ks < 2; ++ks) {
      short8 bBh = frag(sBh[cur], 16 * w + l15, g + 4 * ks);
      short8 bBl = frag(sBl[cur], 16 * w + l15, g + 4 * ks);
#pragma unroll
      for (int rt = 0; rt < 4; ++rt) {
        short8 aAh = frag(sAh[cur], 16 * rt + l15, g + 4 * ks);
        short8 aAl = frag(sAl[cur], 16 * rt + l15, g + 4 * ks);
        acc[rt] = MFMA16(aAh, bBh, acc[rt]);
        acc[rt] = MFMA16(aAh, bBl, acc[rt]);
        acc[rt] = MFMA16(aAl, bBh, acc[rt]);
      }
    }
    __builtin_amdgcn_s_setprio(0);
    WAIT_LGKM0();
    BAR();
    if (h < 6) {
      int hn = h + 2;
      size_t ab = (((size_t)b * HH + hn) * TT + t0) * NN;
      stage_async(sAh[cur], hoh + ab, 64, tid);
      stage_async(sAl[cur], hol + ab, 64, tid);
      stage_async(sBh[cur], wth + hn * 64, 512, tid);
      stage_async(sBl[cur], wtl + hn * 64, 512, tid);
    }
  }
  // epilogue: add x, LayerNorm over the 64 columns
  int mcol = 16 * w + l15;
  float vv[4][4];
#pragma unroll
  for (int rt = 0; rt < 4; ++rt)
#pragma unroll
    for (int r = 0; r < 4; ++r) {
      int row = 16 * rt + 4 * g + r;
      vv[rt][r] = acc[rt][r] + x[((size_t)b * TT + t0 + row) * 64 + mcol];
    }
#pragma unroll
  for (int rt = 0; rt < 4; ++rt)
#pragma unroll
    for (int r = 0; r < 4; ++r) {
      float s1 = vv[rt][r], s2 = vv[rt][r] * vv[rt][r];
#pragma unroll
      for (int mm = 1; mm < 16; mm <<= 1) {
        s1 += __shfl_xor(s1, mm, 64);
        s2 += __shfl_xor(s2, mm, 64);
      }
      if (l15 == 0) {
        int row = 16 * rt + 4 * g + r;
        sred[0][row][w] = s1;
        sred[1][row][w] = s2;
      }
    }
  __syncthreads();
  if (tid < 64) {
    float a1 = sred[0][tid][0] + sred[0][tid][1] + sred[0][tid][2] + sred[0][tid][3];
    float a2 = sred[1][tid][0] + sred[1][tid][1] + sred[1][tid][2] + sred[1][tid][3];
    float mean = a1 * (1.0f / 64.0f);
    float var = a2 * (1.0f / 64.0f) - mean * mean;
    sfin[tid][0] = mean;
    sfin[tid][1] = rsqrtf(var + EPSV);
  }
  __syncthreads();
  float gg = g1l[mcol], bb = b1l[mcol];
#pragma unroll
  for (int rt = 0; rt < 4; ++rt)
#pragma unroll
    for (int r = 0; r < 4; ++r) {
      int row = 16 * rt + 4 * g + r;
      float mean = sfin[row][0], rstd = sfin[row][1];
      out1[((size_t)b * TT + t0 + row) * 64 + mcol] =
          (vv[rt][r] - mean) * rstd * gg + bb;
    }
}

__global__ __launch_bounds__(64) void k_ffn(
    const float* __restrict__ out1, const float* __restrict__ K3sl,
    const float* __restrict__ sclb_l, const float* __restrict__ elWl,
    const float* __restrict__ elbl, const float* __restrict__ g2l,
    const float* __restrict__ b2l, float* __restrict__ xout) {
  __shared__ float so[64], sf[64];
  int lane = threadIdx.x;
  size_t bt = blockIdx.x;
  float o1 = out1[bt * 64 + lane];
  so[lane] = o1;
  __syncthreads();
  float gc = 0.f;
#pragma unroll 8
  for (int n = 0; n < 64; ++n) gc = fmaf(so[n], K3sl[n * 64 + lane], gc);
  float f1 = fmaxf(gc + sclb_l[0] + o1, 0.f);
  sf[lane] = f1;
  __syncthreads();
  float f2 = elbl[lane];
#pragma unroll 8
  for (int e = 0; e < 64; ++e) f2 = fmaf(sf[e], elWl[e * 64 + lane], f2);
  float v = o1 + f2;
  float mu = v;
#pragma unroll
  for (int m = 1; m < 64; m <<= 1) mu += __shfl_xor(mu, m, 64);
  mu *= (1.0f / 64.0f);
  float dd = v - mu;
  float var = dd * dd;
#pragma unroll
  for (int m = 1; m < 64; m <<= 1) var += __shfl_xor(var, m, 64);
  var *= (1.0f / 64.0f);
  xout[bt * 64 + lane] = dd * rsqrtf(var + EPSV) * g2l[lane] + b2l[lane];
}

__global__ __launch_bounds__(256) void k_final(
    const float* __restrict__ x, const float* __restrict__ fW1,
    const float* __restrict__ fb1, const float* __restrict__ fW2,
    const float* __restrict__ fb2, float* __restrict__ out) {
  __shared__ float pl[4][64];
  int tid = threadIdx.x;
  int lane = tid & 63, w = tid >> 6;
  size_t b = blockIdx.x;
  float s = 0.f;
  for (int t = 256 * w; t < 256 * w + 256; ++t) s += x[(b * TT + t) * 64 + lane];
  pl[w][lane] = s;
  __syncthreads();
  if (tid < 64) pl[0][tid] = (pl[0][tid] + pl[1][tid] + pl[2][tid] + pl[3][tid]) * (1.0f / TT);
  __syncthreads();
  if (tid < 64) {
    float hv = 0.f;
    if (lane < 32) {
      hv = fb1[lane];
#pragma unroll 8
      for (int n = 0; n < 64; ++n) hv = fmaf(pl[0][n], fW1[n * 32 + lane], hv);
      hv = fmaxf(hv, 0.f) * fW2[lane];
    }
#pragma unroll
    for (int m = 1; m < 64; m <<= 1) hv += __shfl_xor(hv, m, 64);
    if (lane == 0) out[b] = hv + fb2[0];
  }
}

extern "C" void kernel_launch(void* const* d_in, const int* in_sizes, int n_in,
                              void* d_out, int out_size, void* d_ws, size_t ws_size,
                              hipStream_t stream) {
  const float* inputs = (const float*)d_in[0];
  const float* pos_emb = (const float*)d_in[1];
  const float* K3 = (const float*)d_in[2];
  const float* qw = (const float*)d_in[3];
  const float* qb = (const float*)d_in[4];
  const float* kw = (const float*)d_in[5];
  const float* kb = (const float*)d_in[6];
  const float* vw = (const float*)d_in[7];
  const float* vb = (const float*)d_in[8];
  const float* tqW1 = (const float*)d_in[9];
  const float* tqb1 = (const float*)d_in[10];
  const float* tqW2 = (const float*)d_in[11];
  const float* tqb2 = (const float*)d_in[12];
  const float* tqW3 = (const float*)d_in[13];
  const float* tqb3 = (const float*)d_in[14];
  const float* Wlt = (const float*)d_in[15];
  const float* ln1g = (const float*)d_in[16];
  const float* ln1b = (const float*)d_in[17];
  const float* ln2g = (const float*)d_in[18];
  const float* ln2b = (const float*)d_in[19];
  const float* sclw = (const float*)d_in[20];
  const float* sclb = (const float*)d_in[21];
  const float* elW = (const float*)d_in[22];
  const float* elb = (const float*)d_in[23];
  const float* fW1 = (const float*)d_in[24];
  const float* fb1 = (const float*)d_in[25];
  const float* fW2 = (const float*)d_in[26];
  const float* fb2 = (const float*)d_in[27];
  float* out = (float*)d_out;
  float* ws_f = (float*)d_ws;

  const size_t TN = (size_t)TT * NN;
  const size_t HTN = (size_t)HH * TT * NN;
  const size_t W1T_ELEMS = (size_t)LL * HH * NN * TT;  // ushorts
  const size_t WLT_ELEMS = (size_t)LL * 64 * 512;      // ushorts

  float* K3s = ws_f;
  ushort* w1Th = (ushort*)(ws_f + 2 * 4096);
  ushort* w1Tl = w1Th + W1T_ELEMS;
  ushort* wth = w1Tl + W1T_ELEMS;
  ushort* wtl = wth + WLT_ELEMS;
  const size_t base = 2 * 4096 + W1T_ELEMS + WLT_ELEMS;  // words

  for (int l = 0; l < LL; ++l)
    k_k3s<<<16, 256, 0, stream>>>(K3, sclw + l * KSS, K3s + (size_t)l * 4096);
  k_tsplit<<<LL * HH * 16, 256, 0, stream>>>(tqW1, w1Th, w1Tl);
  k_tsplitW<<<LL * 8, 256, 0, stream>>>(Wlt, wth, wtl);

  const size_t per_b = 2 * TN + 3 * HTN + (size_t)HH * TT + 4 * HTN;
  size_t avail = ws_size / sizeof(float);
  avail = (avail > base) ? avail - base : 0;
  int Bc = (int)(avail / per_b);
  if (Bc > BB) Bc = BB;
  if (Bc < 1) Bc = 1;

  for (int b0 = 0; b0 < BB; b0 += Bc) {
    int bc = (BB - b0 < Bc) ? (BB - b0) : Bc;
    float* x = ws_f + base;
    float* out1 = x + (size_t)bc * TN;
    float* xv = out1 + (size_t)bc * TN;
    float* auv = xv + (size_t)bc * HTN;
    float* h1 = auv + (size_t)bc * HTN;
    float* lseb = h1 + (size_t)bc * HTN;
    ushort* xqh = (ushort*)(lseb + (size_t)bc * HH * TT);
    ushort* xql = xqh + (size_t)bc * HTN;
    ushort* xkh = xql + (size_t)bc * HTN;
    ushort* xkl = xkh + (size_t)bc * HTN;
    ushort* xvTh = xkl + (size_t)bc * HTN;
    ushort* xvTl = xvTh + (size_t)bc * HTN;
    ushort* hoh = xvTl + (size_t)bc * HTN;
    ushort* hol = hoh + (size_t)bc * HTN;

    int total = bc * (int)TN;
    k_addpos<<<(total + 255) / 256, 256, 0, stream>>>(inputs + (size_t)b0 * TN, pos_emb, x,
                                                      total);
    for (int l = 0; l < LL; ++l) {
      k_gconv<<<bc * TT, 64, 0, stream>>>(x, K3, qw + l * HH * KSS, qb + l * HH,
                                          kw + l * HH * KSS, kb + l * HH,
                                          vw + l * HH * KSS, vb + l * HH,
                                          xqh, xql, xkh, xkl, xv);
      k_tsplit<<<bc * HH * 16, 256, 0, stream>>>(xv, xvTh, xvTl);
      k_attn<<<bc * HH * 16, 256, 0, stream>>>(xkh, xkl, xqh, xql, xvTh, xvTl, auv, lseb);
      k_h1<<<bc * HH * 16, 256, 0, stream>>>(
          xkh, xkl, xqh, xql, w1Th + (size_t)l * HH * NN * TT,
          w1Tl + (size_t)l * HH * NN * TT, lseb, tqb1 + l * HH * DD1, h1);
      k_gate<<<bc * HH * (TT / 4), 256, 0, stream>>>(
          h1, xv, tqW2 + (size_t)l * HH * DD1 * DD1, tqb2 + l * HH * DD1,
          tqW3 + (size_t)l * HH * DD1 * 2, tqb3 + l * HH * 2, auv, hoh, hol);
      k_merge<<<bc * 16, 256, 0, stream>>>(x, hoh, hol, wth + (size_t)l * 64 * 512,
                                           wtl + (size_t)l * 64 * 512, ln1g + l * NN,
                                           ln1b + l * NN, out1);
      k_ffn<<<bc * TT, 64, 0, stream>>>(out1, K3s + (size_t)l * 4096, sclb + l,
                                        elW + (size_t)l * NN * NN, elb + l * NN,
                                        ln2g + l * NN, ln2b + l * NN, x);
    }
    k_final<<<bc, 256, 0, stream>>>(x, fW1, fb1, fW2, fb2, out + b0);
  }
}